// Round 8
// baseline (967.579 us; speedup 1.0000x reference)
//
#include <hip/hip_runtime.h>
#include <hip/hip_cooperative_groups.h>
#include <math.h>

namespace cg = cooperative_groups;

#define N 2048
#define D 256
#define H 8
#define DK 32
#define L 4
#define DFF 1024
#define NEDGE 5
#define JC 2  // attention j-split (block parity)

typedef short short8 __attribute__((ext_vector_type(8)));
typedef float floatx4 __attribute__((ext_vector_type(4)));

__device__ __forceinline__ unsigned short f2bf(float f) {
  unsigned int u = __float_as_uint(f);
  u += 0x7fffu + ((u >> 16) & 1u);
  return (unsigned short)(u >> 16);
}

// ---- eidx int32 -> swizzled uint8 -----------------------------------------
// layout: byte for (row i, col j) at ((i/16)*32 + j/64)*1024 + (j%16)*64
//         + ((i/4)%4)*16 + (i%4)*4 + ((j/16)%4)
// so lane (quad,c16) of a 16-row tile fetches its 16 bias indices (4 rows x
// 4 t-positions) of one 64-col j-tile with a single uint4 load.
__global__ __launch_bounds__(256) void k_e8(const int* __restrict__ e,
                                            unsigned char* __restrict__ o) {
  int idx = blockIdx.x * 256 + threadIdx.x;  // over N*N/4
  int i = idx >> 9;        // row
  int jg = idx & 511;
  int tile = jg >> 4;      // 0..31
  int c16 = jg & 15;
  unsigned int b = 0;
#pragma unroll
  for (int t = 0; t < 4; ++t) {
    int j = tile * 64 + t * 16 + c16;
    b |= (unsigned int)(e[(size_t)i * N + j] & 0xff) << (t * 8);
  }
  size_t off = (((size_t)(i >> 4) * 32 + tile) << 10) + (c16 << 6) +
               (((i >> 2) & 3) << 4) + ((i & 3) << 2);
  *(unsigned int*)(o + off) = b;
}

// ---- 4x D x D weight transpose+convert in one launch ----------------------
__global__ __launch_bounds__(256) void k_wt4(const float* __restrict__ Wq,
                                             const float* __restrict__ Wk,
                                             const float* __restrict__ Wv,
                                             const float* __restrict__ Wo,
                                             unsigned short* __restrict__ wqkvb,
                                             unsigned short* __restrict__ wob) {
  __shared__ float t[32][33];
  int z = blockIdx.z, l = z >> 2, which = z & 3;
  const float* s = (which == 0 ? Wq : which == 1 ? Wk : which == 2 ? Wv : Wo) + (size_t)l * D * D;
  unsigned short* d;
  int rowOff;
  if (which < 3) { d = wqkvb + (size_t)l * 768 * D; rowOff = which * 256; }
  else { d = wob + (size_t)l * D * D; rowOff = 0; }
  int n0 = blockIdx.x * 32, k0 = blockIdx.y * 32;
  int tx = threadIdx.x, ty = threadIdx.y;
#pragma unroll
  for (int i = 0; i < 32; i += 8) t[ty + i][tx] = s[(size_t)(k0 + ty + i) * D + n0 + tx];
  __syncthreads();
#pragma unroll
  for (int i = 0; i < 32; i += 8)
    d[(size_t)(rowOff + n0 + ty + i) * D + k0 + tx] = f2bf(t[tx][ty + i]);
}

// ---- generic weight transpose+convert: src fp32 (K_,N_) -> dst bf16 (N_,K_)
__global__ __launch_bounds__(256) void k_wt(const float* __restrict__ src, size_t srcL,
                                            int K_, int N_,
                                            unsigned short* __restrict__ dst, size_t dstL) {
  __shared__ float t[32][33];
  int l = blockIdx.z;
  const float* s = src + (size_t)l * srcL;
  unsigned short* d = dst + (size_t)l * dstL;
  int n0 = blockIdx.x * 32, k0 = blockIdx.y * 32;
  int tx = threadIdx.x, ty = threadIdx.y;
#pragma unroll
  for (int i = 0; i < 32; i += 8) t[ty + i][tx] = s[(size_t)(k0 + ty + i) * N_ + n0 + tx];
  __syncthreads();
#pragma unroll
  for (int i = 0; i < 32; i += 8)
    d[(size_t)(n0 + ty + i) * K_ + k0 + tx] = f2bf(t[tx][ty + i]);
}

// ---------------- persistent cooperative mega-kernel -----------------------
#define PB_STR 72
#define AO_STR 272
#define HS_STR 1040

struct MegaParams {
  const int* nt;
  const float* emb;
  const unsigned short* wqkvb;
  const unsigned short* wob;
  const unsigned short* w1b;
  const unsigned short* w2b;
  const float* bo;
  const float* ebias;
  const float* b1;
  const float* b2;
  const float* g1;
  const float* be1;
  const float* g2;
  const float* be2;
  const float* Wr;
  const float* br;
  const unsigned char* e8s;
  float* x;
  unsigned short* xb;
  unsigned short* qb;
  unsigned short* kb;
  unsigned short* vtb;
  float* Opart;
  float* mpart;
  float* lpart;
  float* ppool;
  float* out;
};

__global__ __launch_bounds__(512, 2) void k_mega(MegaParams P) {
  cg::grid_group grid = cg::this_grid();

  __shared__ union {
    struct { unsigned short Pb[H][16 * PB_STR]; float ebh[H][NEDGE]; } at;
    struct { unsigned short ao[8 * AO_STR]; float redS[8][16]; float redQ[8][16]; } wo;
    struct { unsigned short hs[8 * HS_STR]; float redS[8][16]; float redQ[8][16]; } ff;
    float pool[512];
  } sm;

  const int tid = threadIdx.x;
  const int w = tid >> 6, lane = tid & 63, quad = lane >> 4, c16 = lane & 15;
  const int bid = blockIdx.x;
  const int r0 = bid * 8;

  // ================= embed (own 8 rows) =================
  for (int i = tid; i < 8 * D; i += 512) {
    int r = r0 + (i >> 8);
    int d = i & 255;
    float v = P.emb[P.nt[r] * D + d];
    P.x[(size_t)r * D + d] = v;
    P.xb[(size_t)r * D + d] = f2bf(v);
  }
  // no grid sync needed: QKV reads only own rows

  for (int l = 0; l < L; ++l) {
    // ================= QKV: own 8 rows x 768 cols, rows duplicated =========
    {
      const unsigned short* wq = P.wqkvb + (size_t)l * 768 * D;
      floatx4 qacc[6];
#pragma unroll
      for (int t = 0; t < 6; ++t) qacc[t] = (floatx4){0.f, 0.f, 0.f, 0.f};
#pragma unroll
      for (int kc = 0; kc < 8; ++kc) {
        short8 a = *(const short8*)&P.xb[(size_t)(r0 + (c16 & 7)) * D + kc * 32 + quad * 8];
#pragma unroll
        for (int t = 0; t < 6; ++t) {
          int col = w * 96 + t * 16 + c16;
          short8 bf = *(const short8*)&wq[(size_t)col * D + kc * 32 + quad * 8];
          qacc[t] = __builtin_amdgcn_mfma_f32_16x16x32_bf16(a, bf, qacc[t], 0, 0, 0);
        }
      }
      if (quad < 2) {
#pragma unroll
        for (int t = 0; t < 6; ++t) {
#pragma unroll
          for (int e = 0; e < 4; ++e) {
            int row = r0 + quad * 4 + e;
            int col = w * 96 + t * 16 + c16;
            unsigned short bv = f2bf(qacc[t][e]);
            if (col < 256) P.qb[(size_t)row * D + col] = bv;
            else if (col < 512) P.kb[(size_t)row * D + (col - 256)] = bv;
            else P.vtb[(size_t)(col - 512) * N + row] = bv;
          }
        }
      }
    }
    grid.sync();  // attention needs all rows' Q/K/V

    // ================= attention: 16 rows (block pair) x head-wave =========
    {
      const int r0a = (bid >> 1) * 16;
      const int jc = bid & 1;
      const int h = w;
      if (tid < NEDGE * H) sm.at.ebh[tid % H][tid / H] = P.ebias[(size_t)l * NEDGE * H + tid];
      __syncthreads();

      short8 aq = *(const short8*)&P.qb[(size_t)(r0a + c16) * D + h * DK + quad * 8];
      float mrow[4] = {-INFINITY, -INFINITY, -INFINITY, -INFINITY};
      float lrow[4] = {0.f, 0.f, 0.f, 0.f};
      floatx4 O0 = {0.f, 0.f, 0.f, 0.f};
      floatx4 O1 = {0.f, 0.f, 0.f, 0.f};
      const float scale = 0.17677669529663688f;

      for (int jt = jc * 16; jt < jc * 16 + 16; ++jt) {
        int j0 = jt * 64;
        // hoisted loads: K-frags, V-frags, swizzled e8 (one uint4)
        short8 bk[4];
#pragma unroll
        for (int t = 0; t < 4; ++t)
          bk[t] = *(const short8*)&P.kb[(size_t)(j0 + t * 16 + c16) * D + h * DK + quad * 8];
        short8 pv00 = *(const short8*)&P.vtb[(size_t)(h * DK + c16) * N + j0 + quad * 8];
        short8 pv01 = *(const short8*)&P.vtb[(size_t)(h * DK + c16) * N + j0 + 32 + quad * 8];
        short8 pv10 = *(const short8*)&P.vtb[(size_t)(h * DK + 16 + c16) * N + j0 + quad * 8];
        short8 pv11 = *(const short8*)&P.vtb[(size_t)(h * DK + 16 + c16) * N + j0 + 32 + quad * 8];
        uint4 ew = *(const uint4*)&P.e8s[(((size_t)(r0a >> 4) * 32 + jt) << 10) + (c16 << 6) + (quad << 4)];

        floatx4 Sc[4];
#pragma unroll
        for (int t = 0; t < 4; ++t) {
          floatx4 z = {0.f, 0.f, 0.f, 0.f};
          Sc[t] = __builtin_amdgcn_mfma_f32_16x16x32_bf16(aq, bk[t], z, 0, 0, 0);
        }
        float s[4][4];
        unsigned int ewc[4] = {ew.x, ew.y, ew.z, ew.w};
#pragma unroll
        for (int e = 0; e < 4; ++e)
#pragma unroll
          for (int t = 0; t < 4; ++t)
            s[t][e] = Sc[t][e] * scale + sm.at.ebh[h][(ewc[e] >> (t * 8)) & 0xff];

#pragma unroll
        for (int e = 0; e < 4; ++e) {
          float tm = fmaxf(fmaxf(s[0][e], s[1][e]), fmaxf(s[2][e], s[3][e]));
          tm = fmaxf(tm, __shfl_xor(tm, 1));
          tm = fmaxf(tm, __shfl_xor(tm, 2));
          tm = fmaxf(tm, __shfl_xor(tm, 4));
          tm = fmaxf(tm, __shfl_xor(tm, 8));
          float mn = fmaxf(mrow[e], tm);
          float alpha = __expf(mrow[e] - mn);
          mrow[e] = mn;
          float ps = 0.f;
#pragma unroll
          for (int t = 0; t < 4; ++t) {
            float p = __expf(s[t][e] - mn);
            s[t][e] = p;
            ps += p;
          }
          ps += __shfl_xor(ps, 1);
          ps += __shfl_xor(ps, 2);
          ps += __shfl_xor(ps, 4);
          ps += __shfl_xor(ps, 8);
          lrow[e] = lrow[e] * alpha + ps;
          O0[e] *= alpha;
          O1[e] *= alpha;
        }
#pragma unroll
        for (int t = 0; t < 4; ++t)
#pragma unroll
          for (int e = 0; e < 4; ++e)
            sm.at.Pb[h][(quad * 4 + e) * PB_STR + t * 16 + c16] = f2bf(s[t][e]);
        asm volatile("" ::: "memory");
        short8 ap0 = *(const short8*)&sm.at.Pb[h][c16 * PB_STR + quad * 8];
        short8 ap1 = *(const short8*)&sm.at.Pb[h][c16 * PB_STR + 32 + quad * 8];
        O0 = __builtin_amdgcn_mfma_f32_16x16x32_bf16(ap0, pv00, O0, 0, 0, 0);
        O0 = __builtin_amdgcn_mfma_f32_16x16x32_bf16(ap1, pv01, O0, 0, 0, 0);
        O1 = __builtin_amdgcn_mfma_f32_16x16x32_bf16(ap0, pv10, O1, 0, 0, 0);
        O1 = __builtin_amdgcn_mfma_f32_16x16x32_bf16(ap1, pv11, O1, 0, 0, 0);
        asm volatile("" ::: "memory");
      }

#pragma unroll
      for (int e = 0; e < 4; ++e) {
        int row = r0a + quad * 4 + e;
        size_t ob = ((size_t)jc * N + row) * D + h * DK;
        P.Opart[ob + c16] = O0[e];
        P.Opart[ob + 16 + c16] = O1[e];
        if (c16 == 0) {
          P.mpart[((size_t)jc * N + row) * H + h] = mrow[e];
          P.lpart[((size_t)jc * N + row) * H + h] = lrow[e];
        }
      }
    }
    grid.sync();  // Wo needs both jc partials of its rows

    // ================= Wo: combine -> GEMM -> bias+res+LN1 =================
    {
      const unsigned short* wob = P.wob + (size_t)l * D * D;
      const float* bias = P.bo + (size_t)l * D;
      const float* g = P.g1 + (size_t)l * D;
      const float* b = P.be1 + (size_t)l * D;
      {
        int trow = tid >> 6;
        int tcol = (tid & 63) * 4;
        int hh = tcol >> 5;
        int row = r0 + trow;
        float m[JC], mstar = -INFINITY;
#pragma unroll
        for (int c = 0; c < JC; ++c) {
          m[c] = P.mpart[((size_t)c * N + row) * H + hh];
          mstar = fmaxf(mstar, m[c]);
        }
        float lstar = 0.f;
        float o[4] = {};
#pragma unroll
        for (int c = 0; c < JC; ++c) {
          float wgt = __expf(m[c] - mstar);
          lstar += wgt * P.lpart[((size_t)c * N + row) * H + hh];
          float4 v0 = *(const float4*)(P.Opart + ((size_t)c * N + row) * D + tcol);
          o[0] += wgt * v0.x; o[1] += wgt * v0.y; o[2] += wgt * v0.z; o[3] += wgt * v0.w;
        }
        float inv = 1.0f / lstar;
#pragma unroll
        for (int j = 0; j < 4; ++j) sm.wo.ao[trow * AO_STR + tcol + j] = f2bf(o[j] * inv);
      }
      __syncthreads();

      floatx4 acc[2] = {{0.f, 0.f, 0.f, 0.f}, {0.f, 0.f, 0.f, 0.f}};
#pragma unroll
      for (int kc = 0; kc < 8; ++kc) {
        short8 a = *(const short8*)&sm.wo.ao[(c16 & 7) * AO_STR + kc * 32 + quad * 8];
#pragma unroll
        for (int nt = 0; nt < 2; ++nt) {
          int col = w * 32 + nt * 16 + c16;
          short8 bf = *(const short8*)&wob[(size_t)col * D + kc * 32 + quad * 8];
          acc[nt] = __builtin_amdgcn_mfma_f32_16x16x32_bf16(a, bf, acc[nt], 0, 0, 0);
        }
      }

      float tv[2][4];
      float ps[4];
#pragma unroll
      for (int e = 0; e < 4; ++e) {
        int row = r0 + ((quad * 4 + e) & 7);
        float s = 0.f;
#pragma unroll
        for (int nt = 0; nt < 2; ++nt) {
          int col = w * 32 + nt * 16 + c16;
          float v = acc[nt][e] + bias[col] + P.x[(size_t)row * D + col];
          tv[nt][e] = v;
          s += v;
        }
        s += __shfl_xor(s, 1); s += __shfl_xor(s, 2);
        s += __shfl_xor(s, 4); s += __shfl_xor(s, 8);
        ps[e] = s;
      }
      if (c16 == 0) {
#pragma unroll
        for (int e = 0; e < 4; ++e) sm.wo.redS[w][quad * 4 + e] = ps[e];
      }
      __syncthreads();
      float mean[4];
#pragma unroll
      for (int e = 0; e < 4; ++e) {
        int r = quad * 4 + e;
        mean[e] = (sm.wo.redS[0][r] + sm.wo.redS[1][r] + sm.wo.redS[2][r] + sm.wo.redS[3][r] +
                   sm.wo.redS[4][r] + sm.wo.redS[5][r] + sm.wo.redS[6][r] + sm.wo.redS[7][r]) * (1.0f / D);
        float q = 0.f;
#pragma unroll
        for (int nt = 0; nt < 2; ++nt) {
          float c_ = tv[nt][e] - mean[e];
          q += c_ * c_;
        }
        q += __shfl_xor(q, 1); q += __shfl_xor(q, 2);
        q += __shfl_xor(q, 4); q += __shfl_xor(q, 8);
        ps[e] = q;
      }
      if (c16 == 0) {
#pragma unroll
        for (int e = 0; e < 4; ++e) sm.wo.redQ[w][quad * 4 + e] = ps[e];
      }
      __syncthreads();
#pragma unroll
      for (int e = 0; e < 4; ++e) {
        int r = quad * 4 + e;
        int row = r0 + (r & 7);
        float var = (sm.wo.redQ[0][r] + sm.wo.redQ[1][r] + sm.wo.redQ[2][r] + sm.wo.redQ[3][r] +
                     sm.wo.redQ[4][r] + sm.wo.redQ[5][r] + sm.wo.redQ[6][r] + sm.wo.redQ[7][r]) * (1.0f / D);
        float rs = rsqrtf(var + 1e-5f);
        if (quad < 2) {
#pragma unroll
          for (int nt = 0; nt < 2; ++nt) {
            int col = w * 32 + nt * 16 + c16;
            float o = (tv[nt][e] - mean[e]) * rs * g[col] + b[col];
            P.x[(size_t)row * D + col] = o;
            P.xb[(size_t)row * D + col] = f2bf(o);
          }
        }
      }
    }
    __syncthreads();  // LDS reuse Wo -> FFN (block-local rows, no grid sync)

    // ================= FFN: GEMM1+GELU -> LDS -> GEMM2+bias+res+LN2 ========
    {
      const unsigned short* w1b = P.w1b + (size_t)l * DFF * D;
      const unsigned short* w2b = P.w2b + (size_t)l * D * DFF;
      const float* b1 = P.b1 + (size_t)l * DFF;
      const float* b2 = P.b2 + (size_t)l * D;
      const float* g = P.g2 + (size_t)l * D;
      const float* b = P.be2 + (size_t)l * D;

      floatx4 acc1[8];
#pragma unroll
      for (int nt = 0; nt < 8; ++nt) acc1[nt] = (floatx4){0.f, 0.f, 0.f, 0.f};
#pragma unroll
      for (int kc = 0; kc < 8; ++kc) {
        short8 a = *(const short8*)&P.xb[(size_t)(r0 + (c16 & 7)) * D + kc * 32 + quad * 8];
#pragma unroll
        for (int nt = 0; nt < 8; ++nt) {
          int col = w * 128 + nt * 16 + c16;
          short8 bf = *(const short8*)&w1b[(size_t)col * D + kc * 32 + quad * 8];
          acc1[nt] = __builtin_amdgcn_mfma_f32_16x16x32_bf16(a, bf, acc1[nt], 0, 0, 0);
        }
      }
      if (quad < 2) {
#pragma unroll
        for (int nt = 0; nt < 8; ++nt) {
#pragma unroll
          for (int e = 0; e < 4; ++e) {
            int col = w * 128 + nt * 16 + c16;
            float v = acc1[nt][e] + b1[col];
            v = 0.5f * v * (1.0f + erff(v * 0.70710678118654752f));
            sm.ff.hs[(quad * 4 + e) * HS_STR + col] = f2bf(v);
          }
        }
      }
      __syncthreads();

      floatx4 acc2[2] = {{0.f, 0.f, 0.f, 0.f}, {0.f, 0.f, 0.f, 0.f}};
#pragma unroll 8
      for (int kc = 0; kc < 32; ++kc) {
        short8 a = *(const short8*)&sm.ff.hs[(c16 & 7) * HS_STR + kc * 32 + quad * 8];
#pragma unroll
        for (int nt = 0; nt < 2; ++nt) {
          int col = w * 32 + nt * 16 + c16;
          short8 bf = *(const short8*)&w2b[(size_t)col * DFF + kc * 32 + quad * 8];
          acc2[nt] = __builtin_amdgcn_mfma_f32_16x16x32_bf16(a, bf, acc2[nt], 0, 0, 0);
        }
      }

      float tv[2][4];
      float ps[4];
#pragma unroll
      for (int e = 0; e < 4; ++e) {
        int row = r0 + ((quad * 4 + e) & 7);
        float s = 0.f;
#pragma unroll
        for (int nt = 0; nt < 2; ++nt) {
          int col = w * 32 + nt * 16 + c16;
          float v = acc2[nt][e] + b2[col] + P.x[(size_t)row * D + col];
          tv[nt][e] = v;
          s += v;
        }
        s += __shfl_xor(s, 1); s += __shfl_xor(s, 2);
        s += __shfl_xor(s, 4); s += __shfl_xor(s, 8);
        ps[e] = s;
      }
      if (c16 == 0) {
#pragma unroll
        for (int e = 0; e < 4; ++e) sm.ff.redS[w][quad * 4 + e] = ps[e];
      }
      __syncthreads();
      float mean[4];
#pragma unroll
      for (int e = 0; e < 4; ++e) {
        int r = quad * 4 + e;
        mean[e] = (sm.ff.redS[0][r] + sm.ff.redS[1][r] + sm.ff.redS[2][r] + sm.ff.redS[3][r] +
                   sm.ff.redS[4][r] + sm.ff.redS[5][r] + sm.ff.redS[6][r] + sm.ff.redS[7][r]) * (1.0f / D);
        float q = 0.f;
#pragma unroll
        for (int nt = 0; nt < 2; ++nt) {
          float c_ = tv[nt][e] - mean[e];
          q += c_ * c_;
        }
        q += __shfl_xor(q, 1); q += __shfl_xor(q, 2);
        q += __shfl_xor(q, 4); q += __shfl_xor(q, 8);
        ps[e] = q;
      }
      if (c16 == 0) {
#pragma unroll
        for (int e = 0; e < 4; ++e) sm.ff.redQ[w][quad * 4 + e] = ps[e];
      }
      __syncthreads();
#pragma unroll
      for (int e = 0; e < 4; ++e) {
        int r = quad * 4 + e;
        int row = r0 + (r & 7);
        float var = (sm.ff.redQ[0][r] + sm.ff.redQ[1][r] + sm.ff.redQ[2][r] + sm.ff.redQ[3][r] +
                     sm.ff.redQ[4][r] + sm.ff.redQ[5][r] + sm.ff.redQ[6][r] + sm.ff.redQ[7][r]) * (1.0f / D);
        float rs = rsqrtf(var + 1e-5f);
        if (quad < 2) {
#pragma unroll
          for (int nt = 0; nt < 2; ++nt) {
            int col = w * 32 + nt * 16 + c16;
            float o = (tv[nt][e] - mean[e]) * rs * g[col] + b[col];
            P.x[(size_t)row * D + col] = o;
            P.xb[(size_t)row * D + col] = f2bf(o);
          }
        }
      }
    }
    __syncthreads();  // LDS reuse FFN -> next attention stage
  }

  // ================= pool: per-block partials, then block 0 ================
  if (tid < 256) {
    float s = 0.f, m = -INFINITY;
    for (int r = 0; r < 8; ++r) {
      float v = P.x[(size_t)(r0 + r) * D + tid];
      s += v;
      m = fmaxf(m, v);
    }
    P.ppool[(size_t)bid * 512 + tid] = s;
    P.ppool[(size_t)bid * 512 + 256 + tid] = m;
  }
  grid.sync();
  if (bid == 0) {
    if (tid < 256) {
      float s = 0.f;
      for (int bb = 0; bb < 256; ++bb) s += P.ppool[(size_t)bb * 512 + tid];
      sm.pool[tid] = s * (1.0f / N);
    } else {
      int c = tid - 256;
      float m = -INFINITY;
      for (int bb = 0; bb < 256; ++bb) m = fmaxf(m, P.ppool[(size_t)bb * 512 + 256 + c]);
      sm.pool[tid] = m;
    }
    __syncthreads();
    if (tid < 256) {
      float acc = P.br[tid];
      for (int k2 = 0; k2 < 2 * D; ++k2) acc = fmaf(sm.pool[k2], P.Wr[(size_t)k2 * D + tid], acc);
      P.out[tid] = acc;
    }
  }
}

extern "C" void kernel_launch(void* const* d_in, const int* in_sizes, int n_in,
                              void* d_out, int out_size, void* d_ws, size_t ws_size,
                              hipStream_t stream) {
  const int* node_types = (const int*)d_in[0];
  const int* eidx = (const int*)d_in[1];
  const float* node_emb = (const float*)d_in[2];
  const float* Wq = (const float*)d_in[3];
  const float* Wk = (const float*)d_in[4];
  const float* Wv = (const float*)d_in[5];
  const float* Wo = (const float*)d_in[6];
  const float* bo = (const float*)d_in[7];
  const float* eb = (const float*)d_in[8];
  const float* W1 = (const float*)d_in[9];
  const float* b1 = (const float*)d_in[10];
  const float* W2 = (const float*)d_in[11];
  const float* b2 = (const float*)d_in[12];
  const float* g1 = (const float*)d_in[13];
  const float* be1 = (const float*)d_in[14];
  const float* g2 = (const float*)d_in[15];
  const float* be2 = (const float*)d_in[16];
  const float* Wr = (const float*)d_in[17];
  const float* br = (const float*)d_in[18];
  float* out = (float*)d_out;

  // workspace layout
  float* x = (float*)d_ws;                        // N*D
  float* Opart = x + (size_t)N * D;               // JC*N*D
  float* mpart = Opart + (size_t)JC * N * D;      // JC*N*H
  float* lpart = mpart + (size_t)JC * N * H;      // JC*N*H
  float* ppool = lpart + (size_t)JC * N * H;      // 256*512
  unsigned short* xb = (unsigned short*)(ppool + 256 * 512);
  unsigned short* qb = xb + (size_t)N * D;
  unsigned short* kb = qb + (size_t)N * D;
  unsigned short* vtb = kb + (size_t)N * D;       // (D, N)
  unsigned short* wqkvb = vtb + (size_t)N * D;    // L x (768, 256)
  unsigned short* wob = wqkvb + (size_t)L * 768 * D;
  unsigned short* w1b = wob + (size_t)L * D * D;
  unsigned short* w2b = w1b + (size_t)L * DFF * D;
  unsigned char* e8s = (unsigned char*)(w2b + (size_t)L * D * DFF);  // N*N swizzled

  k_e8<<<(N * N / 4) / 256, 256, 0, stream>>>(eidx, e8s);

  dim3 tb(32, 8);
  k_wt4<<<dim3(D / 32, D / 32, L * 4), tb, 0, stream>>>(Wq, Wk, Wv, Wo, wqkvb, wob);
  k_wt<<<dim3(DFF / 32, D / 32, L), tb, 0, stream>>>(W1, (size_t)D * DFF, D, DFF, w1b, DFF * D);
  k_wt<<<dim3(D / 32, DFF / 32, L), tb, 0, stream>>>(W2, (size_t)DFF * D, DFF, D, w2b, D * DFF);

  MegaParams P;
  P.nt = node_types; P.emb = node_emb;
  P.wqkvb = wqkvb; P.wob = wob; P.w1b = w1b; P.w2b = w2b;
  P.bo = bo; P.ebias = eb; P.b1 = b1; P.b2 = b2;
  P.g1 = g1; P.be1 = be1; P.g2 = g2; P.be2 = be2;
  P.Wr = Wr; P.br = br;
  P.e8s = e8s;
  P.x = x; P.xb = xb; P.qb = qb; P.kb = kb; P.vtb = vtb;
  P.Opart = Opart; P.mpart = mpart; P.lpart = lpart;
  P.ppool = ppool; P.out = out;

  void* args[] = {&P};
  hipLaunchCooperativeKernel((void*)k_mega, dim3(256), dim3(512), args, 0, stream);
}

// Round 9
// 663.751 us; speedup vs baseline: 1.4577x; 1.4577x over previous
//
#include <hip/hip_runtime.h>
#include <math.h>

#define N 2048
#define D 256
#define H 8
#define DK 32
#define L 4
#define DFF 1024
#define NEDGE 5
#define JC 8  // attention j-chunks

typedef short short8 __attribute__((ext_vector_type(8)));
typedef float floatx4 __attribute__((ext_vector_type(4)));

#define LOG2E 1.4426950408889634f

__device__ __forceinline__ unsigned short f2bf(float f) {
  unsigned int u = __float_as_uint(f);
  u += 0x7fffu + ((u >> 16) & 1u);
  return (unsigned short)(u >> 16);
}
__device__ __forceinline__ float bf2f(unsigned short s) {
  unsigned int u = (unsigned int)s << 16;
  return __uint_as_float(u);
}

// ---- eidx int32 -> swizzled uint8 (one uint4 per lane per j-tile) ---------
__global__ __launch_bounds__(256) void k_e8(const int* __restrict__ e,
                                            unsigned char* __restrict__ o) {
  int idx = blockIdx.x * 256 + threadIdx.x;  // over N*N/4
  int i = idx >> 9;
  int jg = idx & 511;
  int tile = jg >> 4;
  int c16 = jg & 15;
  unsigned int b = 0;
#pragma unroll
  for (int t = 0; t < 4; ++t) {
    int j = tile * 64 + t * 16 + c16;
    b |= (unsigned int)(e[(size_t)i * N + j] & 0xff) << (t * 8);
  }
  size_t off = (((size_t)(i >> 4) * 32 + tile) << 10) + (c16 << 6) +
               (((i >> 2) & 3) << 4) + ((i & 3) << 2);
  *(unsigned int*)(o + off) = b;
}

// ---- 4x D x D weight transpose+convert ------------------------------------
__global__ __launch_bounds__(256) void k_wt4(const float* __restrict__ Wq,
                                             const float* __restrict__ Wk,
                                             const float* __restrict__ Wv,
                                             const float* __restrict__ Wo,
                                             unsigned short* __restrict__ wqkvb,
                                             unsigned short* __restrict__ wob) {
  __shared__ float t[32][33];
  int z = blockIdx.z, l = z >> 2, which = z & 3;
  const float* s = (which == 0 ? Wq : which == 1 ? Wk : which == 2 ? Wv : Wo) + (size_t)l * D * D;
  unsigned short* d;
  int rowOff;
  if (which < 3) { d = wqkvb + (size_t)l * 768 * D; rowOff = which * 256; }
  else { d = wob + (size_t)l * D * D; rowOff = 0; }
  int n0 = blockIdx.x * 32, k0 = blockIdx.y * 32;
  int tx = threadIdx.x, ty = threadIdx.y;
#pragma unroll
  for (int i = 0; i < 32; i += 8) t[ty + i][tx] = s[(size_t)(k0 + ty + i) * D + n0 + tx];
  __syncthreads();
#pragma unroll
  for (int i = 0; i < 32; i += 8)
    d[(size_t)(rowOff + n0 + ty + i) * D + k0 + tx] = f2bf(t[tx][ty + i]);
}

__global__ __launch_bounds__(256) void k_wt(const float* __restrict__ src, size_t srcL,
                                            int K_, int N_,
                                            unsigned short* __restrict__ dst, size_t dstL) {
  __shared__ float t[32][33];
  int l = blockIdx.z;
  const float* s = src + (size_t)l * srcL;
  unsigned short* d = dst + (size_t)l * dstL;
  int n0 = blockIdx.x * 32, k0 = blockIdx.y * 32;
  int tx = threadIdx.x, ty = threadIdx.y;
#pragma unroll
  for (int i = 0; i < 32; i += 8) t[ty + i][tx] = s[(size_t)(k0 + ty + i) * N_ + n0 + tx];
  __syncthreads();
#pragma unroll
  for (int i = 0; i < 32; i += 8)
    d[(size_t)(n0 + ty + i) * K_ + k0 + tx] = f2bf(t[tx][ty + i]);
}

// ---------------- embed ----------------------------------------------------
__global__ __launch_bounds__(256) void k_embed(const int* __restrict__ nt,
                                               const float* __restrict__ emb,
                                               float* __restrict__ x,
                                               unsigned short* __restrict__ xb) {
  int n = blockIdx.x, d = threadIdx.x;
  float v = emb[nt[n] * D + d];
  x[n * D + d] = v;
  xb[n * D + d] = f2bf(v);
}

// ---- QKV GEMM, barrier-free, 4 rows/block, 512 blocks ---------------------
__global__ __launch_bounds__(512) void k_qkv(const unsigned short* __restrict__ xb,
                                             const unsigned short* __restrict__ wq,
                                             unsigned short* __restrict__ qb,
                                             unsigned short* __restrict__ kb,
                                             unsigned short* __restrict__ vtb) {
  const int tid = threadIdx.x;
  const int w = tid >> 6, lane = tid & 63, quad = lane >> 4, c16 = lane & 15;
  const int r0 = blockIdx.x * 4;

  floatx4 acc[6];
#pragma unroll
  for (int t = 0; t < 6; ++t) acc[t] = (floatx4){0.f, 0.f, 0.f, 0.f};
#pragma unroll
  for (int kc = 0; kc < 8; ++kc) {
    short8 a = *(const short8*)&xb[(size_t)(r0 + (c16 & 3)) * D + kc * 32 + quad * 8];
#pragma unroll
    for (int t = 0; t < 6; ++t) {
      int col = w * 96 + t * 16 + c16;
      short8 bf = *(const short8*)&wq[(size_t)col * D + kc * 32 + quad * 8];
      acc[t] = __builtin_amdgcn_mfma_f32_16x16x32_bf16(a, bf, acc[t], 0, 0, 0);
    }
  }
  if (quad == 0) {
#pragma unroll
    for (int t = 0; t < 6; ++t) {
#pragma unroll
      for (int e = 0; e < 4; ++e) {
        int row = r0 + e;
        int col = w * 96 + t * 16 + c16;
        unsigned short bv = f2bf(acc[t][e]);
        if (col < 256) qb[(size_t)row * D + col] = bv;
        else if (col < 512) kb[(size_t)row * D + (col - 256)] = bv;
        else vtb[(size_t)(col - 512) * N + row] = bv;
      }
    }
  }
}

// ---- MFMA flash attention, JC=8, exp2 domain, bf16 partials ---------------
#define PB_STR 72
__global__ __launch_bounds__(512) void k_attn(const unsigned short* __restrict__ qb,
                                              const unsigned short* __restrict__ kb,
                                              const unsigned short* __restrict__ vt,
                                              const unsigned char* __restrict__ e8s,
                                              const float* __restrict__ eb,
                                              unsigned short* __restrict__ Opart,
                                              float* __restrict__ mpart,
                                              float* __restrict__ lpart) {
  __shared__ unsigned short Pb[H][16 * PB_STR];
  __shared__ float ebh[H][NEDGE];
  const int tid = threadIdx.x;
  const int h = tid >> 6;
  const int lane = tid & 63;
  const int quad = lane >> 4;
  const int c16 = lane & 15;
  const int r0 = blockIdx.x * 16;
  const int jc = blockIdx.y;

  if (tid < NEDGE * H) ebh[tid % H][tid / H] = eb[tid] * LOG2E;
  __syncthreads();

  short8 aq = *(const short8*)&qb[(size_t)(r0 + c16) * D + h * DK + quad * 8];
  float mrow[4] = {-INFINITY, -INFINITY, -INFINITY, -INFINITY};
  float lrow[4] = {0.f, 0.f, 0.f, 0.f};
  floatx4 O0 = {0.f, 0.f, 0.f, 0.f};
  floatx4 O1 = {0.f, 0.f, 0.f, 0.f};
  const float scale = 0.17677669529663688f * LOG2E;  // exp2 domain

  for (int jt = jc * (32 / JC); jt < (jc + 1) * (32 / JC); ++jt) {
    int j0 = jt * 64;
    short8 bk[4];
#pragma unroll
    for (int t = 0; t < 4; ++t)
      bk[t] = *(const short8*)&kb[(size_t)(j0 + t * 16 + c16) * D + h * DK + quad * 8];
    short8 pv00 = *(const short8*)&vt[(size_t)(h * DK + c16) * N + j0 + quad * 8];
    short8 pv01 = *(const short8*)&vt[(size_t)(h * DK + c16) * N + j0 + 32 + quad * 8];
    short8 pv10 = *(const short8*)&vt[(size_t)(h * DK + 16 + c16) * N + j0 + quad * 8];
    short8 pv11 = *(const short8*)&vt[(size_t)(h * DK + 16 + c16) * N + j0 + 32 + quad * 8];
    uint4 ew = *(const uint4*)&e8s[(((size_t)(r0 >> 4) * 32 + jt) << 10) + (c16 << 6) + (quad << 4)];

    floatx4 Sc[4];
#pragma unroll
    for (int t = 0; t < 4; ++t) {
      floatx4 z = {0.f, 0.f, 0.f, 0.f};
      Sc[t] = __builtin_amdgcn_mfma_f32_16x16x32_bf16(aq, bk[t], z, 0, 0, 0);
    }
    float s[4][4];
    unsigned int ewc[4] = {ew.x, ew.y, ew.z, ew.w};
#pragma unroll
    for (int e = 0; e < 4; ++e)
#pragma unroll
      for (int t = 0; t < 4; ++t)
        s[t][e] = Sc[t][e] * scale + ebh[h][(ewc[e] >> (t * 8)) & 0xff];

#pragma unroll
    for (int e = 0; e < 4; ++e) {
      float tm = fmaxf(fmaxf(s[0][e], s[1][e]), fmaxf(s[2][e], s[3][e]));
      tm = fmaxf(tm, __shfl_xor(tm, 1));
      tm = fmaxf(tm, __shfl_xor(tm, 2));
      tm = fmaxf(tm, __shfl_xor(tm, 4));
      tm = fmaxf(tm, __shfl_xor(tm, 8));
      float mn = fmaxf(mrow[e], tm);
      float alpha = exp2f(mrow[e] - mn);
      mrow[e] = mn;
      float ps = 0.f;
#pragma unroll
      for (int t = 0; t < 4; ++t) {
        float p = exp2f(s[t][e] - mn);
        s[t][e] = p;
        ps += p;
      }
      ps += __shfl_xor(ps, 1);
      ps += __shfl_xor(ps, 2);
      ps += __shfl_xor(ps, 4);
      ps += __shfl_xor(ps, 8);
      lrow[e] = lrow[e] * alpha + ps;
      O0[e] *= alpha;
      O1[e] *= alpha;
    }
#pragma unroll
    for (int t = 0; t < 4; ++t)
#pragma unroll
      for (int e = 0; e < 4; ++e)
        Pb[h][(quad * 4 + e) * PB_STR + t * 16 + c16] = f2bf(s[t][e]);
    asm volatile("" ::: "memory");
    short8 ap0 = *(const short8*)&Pb[h][c16 * PB_STR + quad * 8];
    short8 ap1 = *(const short8*)&Pb[h][c16 * PB_STR + 32 + quad * 8];
    O0 = __builtin_amdgcn_mfma_f32_16x16x32_bf16(ap0, pv00, O0, 0, 0, 0);
    O0 = __builtin_amdgcn_mfma_f32_16x16x32_bf16(ap1, pv01, O0, 0, 0, 0);
    O1 = __builtin_amdgcn_mfma_f32_16x16x32_bf16(ap0, pv10, O1, 0, 0, 0);
    O1 = __builtin_amdgcn_mfma_f32_16x16x32_bf16(ap1, pv11, O1, 0, 0, 0);
    asm volatile("" ::: "memory");
  }

#pragma unroll
  for (int e = 0; e < 4; ++e) {
    int row = r0 + quad * 4 + e;
    size_t ob = ((size_t)jc * N + row) * D + h * DK;
    Opart[ob + c16] = f2bf(O0[e]);
    Opart[ob + 16 + c16] = f2bf(O1[e]);
    if (c16 == 0) {
      mpart[((size_t)jc * N + row) * H + h] = mrow[e];  // log2 domain
      lpart[((size_t)jc * N + row) * H + h] = lrow[e];
    }
  }
}

// ---- fused: combine(exp2) -> Wo GEMM -> bias+residual+LN1 -----------------
// 4 rows/block, 512 blocks, 512 threads; MFMA rows duplicated 4x.
#define AO_STR 264
__global__ __launch_bounds__(512) void k_wo(const unsigned short* __restrict__ Opart,
                                            const float* __restrict__ mpart,
                                            const float* __restrict__ lpart,
                                            const unsigned short* __restrict__ wob,
                                            const float* __restrict__ bias,
                                            const float* __restrict__ g,
                                            const float* __restrict__ b,
                                            float* __restrict__ x,
                                            unsigned short* __restrict__ xb) {
  __shared__ unsigned short ao_s[4 * AO_STR];
  __shared__ float redS[8][4];
  __shared__ float redQ[8][4];
  const int tid = threadIdx.x;
  const int w = tid >> 6, lane = tid & 63, quad = lane >> 4, c16 = lane & 15;
  const int r0 = blockIdx.x * 4;

  // combine: 4 rows x 256 cols, 2 cols/thread
  {
    int trow = tid >> 7;
    int tcol = (tid & 127) * 2;
    int hh = tcol >> 5;
    int row = r0 + trow;
    float m[JC], mstar = -INFINITY;
#pragma unroll
    for (int c = 0; c < JC; ++c) {
      m[c] = mpart[((size_t)c * N + row) * H + hh];
      mstar = fmaxf(mstar, m[c]);
    }
    float lstar = 0.f, o0 = 0.f, o1 = 0.f;
#pragma unroll
    for (int c = 0; c < JC; ++c) {
      float wgt = exp2f(m[c] - mstar);
      lstar += wgt * lpart[((size_t)c * N + row) * H + hh];
      unsigned int pr = *(const unsigned int*)&Opart[((size_t)c * N + row) * D + tcol];
      o0 += wgt * bf2f((unsigned short)(pr & 0xffff));
      o1 += wgt * bf2f((unsigned short)(pr >> 16));
    }
    float inv = 1.0f / lstar;
    ao_s[trow * AO_STR + tcol] = f2bf(o0 * inv);
    ao_s[trow * AO_STR + tcol + 1] = f2bf(o1 * inv);
  }
  __syncthreads();

  floatx4 acc[2] = {{0.f, 0.f, 0.f, 0.f}, {0.f, 0.f, 0.f, 0.f}};
#pragma unroll
  for (int kc = 0; kc < 8; ++kc) {
    short8 a = *(const short8*)&ao_s[(c16 & 3) * AO_STR + kc * 32 + quad * 8];
#pragma unroll
    for (int nt = 0; nt < 2; ++nt) {
      int col = w * 32 + nt * 16 + c16;
      short8 bf = *(const short8*)&wob[(size_t)col * D + kc * 32 + quad * 8];
      acc[nt] = __builtin_amdgcn_mfma_f32_16x16x32_bf16(a, bf, acc[nt], 0, 0, 0);
    }
  }

  // epilogue: all quads hold the same 4 rows (e=0..3); reduce over c16 lanes.
  float tv[2][4];
  float ps[4];
#pragma unroll
  for (int e = 0; e < 4; ++e) {
    int row = r0 + e;
    float s = 0.f;
#pragma unroll
    for (int nt = 0; nt < 2; ++nt) {
      int col = w * 32 + nt * 16 + c16;
      float v = acc[nt][e] + bias[col] + x[(size_t)row * D + col];
      tv[nt][e] = v;
      s += v;
    }
    s += __shfl_xor(s, 1); s += __shfl_xor(s, 2);
    s += __shfl_xor(s, 4); s += __shfl_xor(s, 8);
    ps[e] = s;
  }
  if (lane == 0) {
#pragma unroll
    for (int e = 0; e < 4; ++e) redS[w][e] = ps[e];
  }
  __syncthreads();
  float mean[4];
#pragma unroll
  for (int e = 0; e < 4; ++e) {
    mean[e] = (redS[0][e] + redS[1][e] + redS[2][e] + redS[3][e] +
               redS[4][e] + redS[5][e] + redS[6][e] + redS[7][e]) * (1.0f / D);
    float q = 0.f;
#pragma unroll
    for (int nt = 0; nt < 2; ++nt) {
      float c_ = tv[nt][e] - mean[e];
      q += c_ * c_;
    }
    q += __shfl_xor(q, 1); q += __shfl_xor(q, 2);
    q += __shfl_xor(q, 4); q += __shfl_xor(q, 8);
    ps[e] = q;
  }
  if (lane == 0) {
#pragma unroll
    for (int e = 0; e < 4; ++e) redQ[w][e] = ps[e];
  }
  __syncthreads();
  if (quad == 0) {
#pragma unroll
    for (int e = 0; e < 4; ++e) {
      int row = r0 + e;
      float var = (redQ[0][e] + redQ[1][e] + redQ[2][e] + redQ[3][e] +
                   redQ[4][e] + redQ[5][e] + redQ[6][e] + redQ[7][e]) * (1.0f / D);
      float rs = rsqrtf(var + 1e-5f);
#pragma unroll
      for (int nt = 0; nt < 2; ++nt) {
        int col = w * 32 + nt * 16 + c16;
        float o = (tv[nt][e] - mean[e]) * rs * g[col] + b[col];
        x[(size_t)row * D + col] = o;
        xb[(size_t)row * D + col] = f2bf(o);
      }
    }
  }
}

// ---- FFN1: 8 rows x 512 cols (DFF half) per block, 512 blocks, no LDS -----
__global__ __launch_bounds__(512) void k_ffn1(const unsigned short* __restrict__ xb,
                                              const unsigned short* __restrict__ w1b,
                                              const float* __restrict__ b1,
                                              unsigned short* __restrict__ hb) {
  const int tid = threadIdx.x;
  const int w = tid >> 6, lane = tid & 63, quad = lane >> 4, c16 = lane & 15;
  const int r0 = blockIdx.y * 8;
  const int ch = blockIdx.x;  // DFF half

  floatx4 acc[4];
#pragma unroll
  for (int t = 0; t < 4; ++t) acc[t] = (floatx4){0.f, 0.f, 0.f, 0.f};
#pragma unroll
  for (int kc = 0; kc < 8; ++kc) {
    short8 a = *(const short8*)&xb[(size_t)(r0 + (c16 & 7)) * D + kc * 32 + quad * 8];
#pragma unroll
    for (int t = 0; t < 4; ++t) {
      int col = ch * 512 + w * 64 + t * 16 + c16;
      short8 bf = *(const short8*)&w1b[(size_t)col * D + kc * 32 + quad * 8];
      acc[t] = __builtin_amdgcn_mfma_f32_16x16x32_bf16(a, bf, acc[t], 0, 0, 0);
    }
  }
  if (quad < 2) {
#pragma unroll
    for (int t = 0; t < 4; ++t) {
#pragma unroll
      for (int e = 0; e < 4; ++e) {
        int row = r0 + quad * 4 + e;
        int col = ch * 512 + w * 64 + t * 16 + c16;
        float v = acc[t][e] + b1[col];
        v = 0.5f * v * (1.0f + erff(v * 0.70710678118654752f));
        hb[(size_t)row * DFF + col] = f2bf(v);
      }
    }
  }
}

// ---- FFN2: 8 rows, K-half partials -> tmp fp32, 512 blocks, no LDS --------
__global__ __launch_bounds__(512) void k_ffn2(const unsigned short* __restrict__ hb,
                                              const unsigned short* __restrict__ w2b,
                                              float* __restrict__ tmp0,
                                              float* __restrict__ tmp1) {
  const int tid = threadIdx.x;
  const int w = tid >> 6, lane = tid & 63, quad = lane >> 4, c16 = lane & 15;
  const int r0 = blockIdx.y * 8;
  const int kh = blockIdx.x;  // K half

  floatx4 acc[2] = {{0.f, 0.f, 0.f, 0.f}, {0.f, 0.f, 0.f, 0.f}};
#pragma unroll
  for (int kc = 0; kc < 16; ++kc) {
    short8 a = *(const short8*)&hb[(size_t)(r0 + (c16 & 7)) * DFF + kh * 512 + kc * 32 + quad * 8];
#pragma unroll
    for (int nt = 0; nt < 2; ++nt) {
      int col = w * 32 + nt * 16 + c16;
      short8 bf = *(const short8*)&w2b[(size_t)col * DFF + kh * 512 + kc * 32 + quad * 8];
      acc[nt] = __builtin_amdgcn_mfma_f32_16x16x32_bf16(a, bf, acc[nt], 0, 0, 0);
    }
  }
  float* tp = kh ? tmp1 : tmp0;
  if (quad < 2) {
#pragma unroll
    for (int nt = 0; nt < 2; ++nt) {
#pragma unroll
      for (int e = 0; e < 4; ++e) {
        int row = r0 + quad * 4 + e;
        int col = w * 32 + nt * 16 + c16;
        tp[(size_t)row * D + col] = acc[nt][e];
      }
    }
  }
}

// ---- residual + partial-sum + bias + layernorm ----------------------------
__global__ __launch_bounds__(256) void k_add_ln3(const float* __restrict__ x,
                                                 const float* __restrict__ t0,
                                                 const float* __restrict__ t1,
                                                 const float* __restrict__ bias,
                                                 const float* __restrict__ g,
                                                 const float* __restrict__ b,
                                                 float* __restrict__ outx,
                                                 unsigned short* __restrict__ outb) {
  __shared__ float s[256];
  int row = blockIdx.x, d = threadIdx.x;
  size_t i = (size_t)row * D + d;
  float t = x[i] + t0[i] + t1[i] + bias[d];
  s[d] = t;
  __syncthreads();
#pragma unroll
  for (int off = 128; off; off >>= 1) {
    if (d < off) s[d] += s[d + off];
    __syncthreads();
  }
  float mean = s[0] * (1.0f / D);
  __syncthreads();
  float c = t - mean;
  s[d] = c * c;
  __syncthreads();
#pragma unroll
  for (int off = 128; off; off >>= 1) {
    if (d < off) s[d] += s[d + off];
    __syncthreads();
  }
  float var = s[0] * (1.0f / D);
  float r = rsqrtf(var + 1e-5f);
  float o = c * r * g[d] + b[d];
  outx[i] = o;
  outb[i] = f2bf(o);
}

// ---- pool phase 1: 256 blocks x 8 rows ------------------------------------
__global__ __launch_bounds__(256) void k_pool1(const float* __restrict__ x,
                                               float* __restrict__ part) {
  int b = blockIdx.x, d = threadIdx.x;
  float sum = 0.f, mx = -INFINITY;
  for (int n = b * 8; n < b * 8 + 8; ++n) {
    float v = x[(size_t)n * D + d];
    sum += v;
    mx = fmaxf(mx, v);
  }
  part[(size_t)b * 2 * D + d] = sum;
  part[(size_t)b * 2 * D + D + d] = mx;
}

__global__ __launch_bounds__(256) void k_pool2(const float* __restrict__ part,
                                               const float* __restrict__ Wr,
                                               const float* __restrict__ br,
                                               float* __restrict__ out) {
  __shared__ float pooled[2 * D];
  int d = threadIdx.x;
  float sum = 0.f, mx = -INFINITY;
  for (int b = 0; b < 256; ++b) {
    sum += part[(size_t)b * 2 * D + d];
    mx = fmaxf(mx, part[(size_t)b * 2 * D + D + d]);
  }
  pooled[d] = sum * (1.0f / N);
  pooled[D + d] = mx;
  __syncthreads();
  float acc = br[d];
  for (int k2 = 0; k2 < 2 * D; ++k2) acc = fmaf(pooled[k2], Wr[(size_t)k2 * D + d], acc);
  out[d] = acc;
}

extern "C" void kernel_launch(void* const* d_in, const int* in_sizes, int n_in,
                              void* d_out, int out_size, void* d_ws, size_t ws_size,
                              hipStream_t stream) {
  const int* node_types = (const int*)d_in[0];
  const int* eidx = (const int*)d_in[1];
  const float* node_emb = (const float*)d_in[2];
  const float* Wq = (const float*)d_in[3];
  const float* Wk = (const float*)d_in[4];
  const float* Wv = (const float*)d_in[5];
  const float* Wo = (const float*)d_in[6];
  const float* bo = (const float*)d_in[7];
  const float* eb = (const float*)d_in[8];
  const float* W1 = (const float*)d_in[9];
  const float* b1 = (const float*)d_in[10];
  const float* W2 = (const float*)d_in[11];
  const float* b2 = (const float*)d_in[12];
  const float* g1 = (const float*)d_in[13];
  const float* be1 = (const float*)d_in[14];
  const float* g2 = (const float*)d_in[15];
  const float* be2 = (const float*)d_in[16];
  const float* Wr = (const float*)d_in[17];
  const float* br = (const float*)d_in[18];
  float* out = (float*)d_out;

  // workspace layout
  float* x = (float*)d_ws;                       // N*D
  float* tmp0 = x + (size_t)N * D;               // N*D
  float* tmp1 = tmp0 + (size_t)N * D;            // N*D
  float* mpart = tmp1 + (size_t)N * D;           // JC*N*H
  float* lpart = mpart + (size_t)JC * N * H;     // JC*N*H
  float* ppool = lpart + (size_t)JC * N * H;     // 256*2*D
  unsigned short* xb = (unsigned short*)(ppool + 256 * 2 * D);
  unsigned short* qb = xb + (size_t)N * D;
  unsigned short* kb = qb + (size_t)N * D;
  unsigned short* vtb = kb + (size_t)N * D;      // (D, N)
  unsigned short* hb = vtb + (size_t)N * D;      // N*DFF
  unsigned short* Opart = hb + (size_t)N * DFF;  // JC*N*D bf16
  unsigned short* wqkvb = Opart + (size_t)JC * N * D;
  unsigned short* wob = wqkvb + (size_t)L * 768 * D;
  unsigned short* w1b = wob + (size_t)L * D * D;
  unsigned short* w2b = w1b + (size_t)L * DFF * D;
  unsigned char* e8s = (unsigned char*)(w2b + (size_t)L * D * DFF);

  k_e8<<<(N * N / 4) / 256, 256, 0, stream>>>(eidx, e8s);

  dim3 tb(32, 8);
  k_wt4<<<dim3(D / 32, D / 32, L * 4), tb, 0, stream>>>(Wq, Wk, Wv, Wo, wqkvb, wob);
  k_wt<<<dim3(DFF / 32, D / 32, L), tb, 0, stream>>>(W1, (size_t)D * DFF, D, DFF, w1b, DFF * D);
  k_wt<<<dim3(D / 32, DFF / 32, L), tb, 0, stream>>>(W2, (size_t)DFF * D, DFF, D, w2b, D * DFF);

  k_embed<<<N, 256, 0, stream>>>(node_types, node_emb, x, xb);

  for (int l = 0; l < L; ++l) {
    k_qkv<<<N / 4, 512, 0, stream>>>(xb, wqkvb + (size_t)l * 768 * D, qb, kb, vtb);

    k_attn<<<dim3(N / 16, JC), 512, 0, stream>>>(qb, kb, vtb, e8s,
                                                 eb + (size_t)l * NEDGE * H,
                                                 Opart, mpart, lpart);

    k_wo<<<N / 4, 512, 0, stream>>>(Opart, mpart, lpart,
                                    wob + (size_t)l * D * D, bo + (size_t)l * D,
                                    g1 + (size_t)l * D, be1 + (size_t)l * D, x, xb);

    k_ffn1<<<dim3(2, N / 8), 512, 0, stream>>>(xb, w1b + (size_t)l * DFF * D,
                                               b1 + (size_t)l * DFF, hb);
    k_ffn2<<<dim3(2, N / 8), 512, 0, stream>>>(hb, w2b + (size_t)l * D * DFF, tmp0, tmp1);
    k_add_ln3<<<N, 256, 0, stream>>>(x, tmp0, tmp1, b2 + (size_t)l * D,
                                     g2 + (size_t)l * D, be2 + (size_t)l * D, x, xb);
  }

  k_pool1<<<256, 256, 0, stream>>>(x, ppool);
  k_pool2<<<1, 256, 0, stream>>>(ppool, Wr, br, out);
}